// Round 5
// baseline (618.161 us; speedup 1.0000x reference)
//
#include <hip/hip_runtime.h>
#include <hip/hip_bf16.h>

using bf16 = __hip_bfloat16;
typedef short short8  __attribute__((ext_vector_type(8)));   // 8 bf16 (4 VGPRs) MFMA frag
typedef short short4v __attribute__((ext_vector_type(4)));
typedef float f32x4   __attribute__((ext_vector_type(4)));   // MFMA accumulator

static __device__ __forceinline__ bf16  f2b(float v){ return __float2bfloat16(v); }
static __device__ __forceinline__ float s2f(short s){ return __bfloat162float(__builtin_bit_cast(bf16, s)); }
static __device__ __forceinline__ short f2s(float f){ return __builtin_bit_cast(short, __float2bfloat16(f)); }

// fallback path: load 8 consecutive fp32 weights -> bf16x8 MFMA fragment
static __device__ __forceinline__ short8 ldw8(const float* __restrict__ p){
  const float4 u = *(const float4*)(p);
  const float4 v = *(const float4*)(p + 4);
  short8 r;
  r[0]=f2s(u.x); r[1]=f2s(u.y); r[2]=f2s(u.z); r[3]=f2s(u.w);
  r[4]=f2s(v.x); r[5]=f2s(v.y); r[6]=f2s(v.z); r[7]=f2s(v.w);
  return r;
}

#define MFMA16(a,b,c) __builtin_amdgcn_mfma_f32_16x16x32_bf16((a),(b),(c),0,0,0)

// bank-conflict swizzle: XOR byte-in-row bits 4..5 with (row>>2)&3.
// C-writes (rows row0..row0+3) get key==quad -> quads use disjoint bank sets.
// b128 frag reads (row m0+l15) get key==(l15>>2)&3; 16B blocks relocate intact,
// so writer/reader agree as long as BOTH apply the same formula on the same row.
#define KEYR(row) ((((row) >> 2) & 3) << 4)

constexpr int TPB = 256;
constexpr float EPS = 1e-5f;
constexpr float QSC = 0.17677669529663687f;   // 32^-0.5

// ---- d_ws layout: pre-converted bf16 weights + dense rel-pos bias table
constexpr int WQ_OFF  = 0;        // qkvw  288x96 bf16 (q rows pre-scaled by QSC)
constexpr int WPJ_OFF = 27648;    // projw  96x96
constexpr int WF1_OFF = 36864;    // fc1w  192x96
constexpr int WF2_OFF = 55296;    // fc2w  96x192
constexpr int WTOT    = 73728;    // total bf16 weight elements
constexpr int BTAB_BYTE_OFF = 147456;          // fp32 [3][64][64]
constexpr size_t WS_NEEDED = 147456 + 49152;   // 196,608 B

// ---- LDS regions (byte offsets). TWO windows per block (rows 0..63 = win0, 64..127 = win1).
//  R0 (26624): s_a [128][208B] (x/LN1) -> q[128][80B]+k[128][80B] -> proj+LN2 -> s_at [96][272B]
//  R1 (26624): s_ao [128][208B] (attn out) -> low part of s_h
//  R2 (27648): vt [2][32][144B] + p [128][144B] -> high part of s_h
//  s_h [128][400B] (fc1 out) spans R1+R2 (51200 <= 54272)
constexpr int R0_OFF = 0;
constexpr int R1_OFF = 26624;
constexpr int R2_OFF = 53248;
constexpr int SMEM_BYTES = 80896;   // *2 = 161,792 <= 163,840 -> 2 blocks/CU (8 waves)

__global__ void init_ws_kernel(
    const float* __restrict__ qkvw, const float* __restrict__ projw,
    const float* __restrict__ fc1w, const float* __restrict__ fc2w,
    const float* __restrict__ rpb,
    bf16* __restrict__ wbf, float* __restrict__ btab)
{
  const int i = blockIdx.x * 256 + threadIdx.x;
  if (i < WTOT){
    float v;
    if (i < WPJ_OFF)      v = qkvw[i];
    else if (i < WF1_OFF) v = projw[i - WPJ_OFF];
    else if (i < WF2_OFF) v = fc1w[i - WF1_OFF];
    else                  v = fc2w[i - WF2_OFF];
    if (i < 9216) v *= QSC;          // q-section rows 0..95: fold 1/sqrt(d)
    wbf[i] = f2b(v);
  }
  if (i < 3*64*64){
    const int h   = i >> 12;
    const int row = (i >> 6) & 63;
    const int col = i & 63;
    const int rel = ((row>>3) - (col>>3) + 7)*15 + ((row&7) - (col&7) + 7);
    btab[i] = rpb[rel*3 + h];
  }
}

template<bool PRE>
__global__ __launch_bounds__(TPB, 2) void swin_block_kernel(
    const float* __restrict__ x,
    const float* __restrict__ qkvw,  const float* __restrict__ qkvb,
    const float* __restrict__ projw, const float* __restrict__ projb,
    const float* __restrict__ rpb,
    const float* __restrict__ n1g,   const float* __restrict__ n1b,
    const float* __restrict__ n2g,   const float* __restrict__ n2b,
    const float* __restrict__ fc1w,  const float* __restrict__ fc1b,
    const float* __restrict__ fc2w,  const float* __restrict__ fc2b,
    float* __restrict__ out,
    const bf16* __restrict__ wbf,    const float* __restrict__ btab)
{
  __shared__ alignas(16) unsigned char smem[SMEM_BYTES];
  char* s_a  = (char*)(smem + R0_OFF);           // [128] rows of 208 B (swizzled)
  char* s_q  = (char*)(smem + R0_OFF);           // [128] rows of 80 B  (swizzled)
  char* s_k  = (char*)(smem + R0_OFF + 10240);   // [128] rows of 80 B  (swizzled)
  char* s_at = (char*)(smem + R0_OFF);           // [96]  rows of 272 B (plain)
  char* s_ao = (char*)(smem + R1_OFF);           // [128] rows of 208 B (swizzled)
  char* s_h  = (char*)(smem + R1_OFF);           // [128] rows of 400 B (swizzled, spans R1+R2)
  char* s_vt = (char*)(smem + R2_OFF);           // [2][32] rows of 144 B (swizzled on d)
  char* s_p  = (char*)(smem + R2_OFF + 9216);    // [128] rows of 144 B (swizzled)

  const bf16* wQ  = wbf + WQ_OFF;
  const bf16* wP  = wbf + WPJ_OFF;
  const bf16* wF1 = wbf + WF1_OFF;
  const bf16* wF2 = wbf + WF2_OFF;

  const int tid  = threadIdx.x;
  const int wid  = tid >> 6;
  const int lane = tid & 63;
  const int quad = lane >> 4;
  const int l15  = lane & 15;
  const int m0   = wid * 16;       // wave's m-tile rows within a window
  const int row0 = m0 + quad * 4;  // C/D frag rows (within window)
  const int cwz  = quad << 4;          // write-side XOR key (rows row0..row0+3)
  const int rwz  = ((l15 >> 2) & 3) << 4;   // read-side XOR key (row m0+l15 / nt*16+l15)

  // grid 4096: 8 batch x 32 wh x 16 window-pairs (2 adjacent windows along W)
  const int blk = blockIdx.x;
  const int b    = blk >> 9;
  const int wh   = (blk >> 4) & 31;
  const int wcol = blk & 15;
  const size_t base = ((size_t)b * 96) * 65536 + (size_t)wh * 2048 + (size_t)wcol * 16;
  // element (c, i, j) at base + c*65536 + i*256 + j ; j in [0,16): win = j>>3, token = i*8 + (j&7)

  // ---------------- load x (float4), keep in regs for residual ----
  float4 xsave[12];
  #pragma unroll
  for (int it = 0; it < 12; it++){
    const int idx4 = it*256 + tid;
    const int c = idx4 >> 5, r = idx4 & 31;
    const int irow = r >> 2, j0 = (r & 3) * 4;
    const float4 xv = *(const float4*)(x + base + (size_t)c*65536 + irow*256 + j0);
    xsave[it] = xv;
    const int srow = (j0 >> 3)*64 + irow*8 + (j0 & 7);   // multiple of 4
    const int co = (c*2) ^ KEYR(srow);
    *(bf16*)(s_a + (srow+0)*208 + co) = f2b(xv.x);
    *(bf16*)(s_a + (srow+1)*208 + co) = f2b(xv.y);
    *(bf16*)(s_a + (srow+2)*208 + co) = f2b(xv.z);
    *(bf16*)(s_a + (srow+3)*208 + co) = f2b(xv.w);
  }
  __syncthreads();

  // ---------------- LN1: 4 threads/row, 2 windows, wave-private rows ----
  {
    const int rr = tid >> 2, s = tid & 3;
    const int cb = s*24;
    const int key = KEYR(rr);          // (64+rr) has the same key
    float gv[24], bb[24];
    #pragma unroll
    for (int u = 0; u < 6; u++){
      const float4 g4 = *(const float4*)(n1g + cb + u*4);
      const float4 b4 = *(const float4*)(n1b + cb + u*4);
      gv[u*4+0]=g4.x; gv[u*4+1]=g4.y; gv[u*4+2]=g4.z; gv[u*4+3]=g4.w;
      bb[u*4+0]=b4.x; bb[u*4+1]=b4.y; bb[u*4+2]=b4.z; bb[u*4+3]=b4.w;
    }
    #pragma unroll
    for (int wv = 0; wv < 2; wv++){
      char* row = s_a + (wv*64 + rr)*208;
      float vals[24];
      float sum = 0.f, sq = 0.f;
      #pragma unroll
      for (int u = 0; u < 3; u++){
        short8 v8 = *(const short8*)(row + (((cb + u*8)*2) ^ key));
        #pragma unroll
        for (int j = 0; j < 8; j++){ float f = s2f(v8[j]); vals[u*8+j] = f; sum += f; sq += f*f; }
      }
      sum += __shfl_xor(sum, 1); sum += __shfl_xor(sum, 2);
      sq  += __shfl_xor(sq , 1); sq  += __shfl_xor(sq , 2);
      const float mu  = sum * (1.f/96.f);
      const float inv = rsqrtf(fmaxf(sq*(1.f/96.f) - mu*mu, 0.f) + EPS);
      #pragma unroll
      for (int u = 0; u < 3; u++){
        short8 o8;
        #pragma unroll
        for (int j = 0; j < 8; j++)
          o8[j] = f2s((vals[u*8+j] - mu) * inv * gv[u*8+j] + bb[u*8+j]);
        *(short8*)(row + (((cb + u*8)*2) ^ key)) = o8;
      }
    }
  }

  const f32x4 zac = {0.f, 0.f, 0.f, 0.f};

  // A-fragments of LN1(x) for both windows (registers; s_a then dead)
  short8 A0[2], A1[2], A2[2];
  #pragma unroll
  for (int wv = 0; wv < 2; wv++){
    const char* ap = s_a + (wv*64 + m0 + l15)*208;
    const int q16 = (quad*16) ^ rwz;
    A0[wv] = *(const short8*)(ap + q16);
    A1[wv] = *(const short8*)(ap + q16 + 64);
    A2[wv] = *(const short8*)(ap + q16 + 128);
  }
  __syncthreads();   // all waves hoisted before q/k overwrite R0

  // ---------------- attention: head at a time; 2 barriers/head; both windows ----
  for (int h = 0; h < 3; h++){
    // ---- qkv_h : per nt, shared W-fragments serve both windows
    #pragma unroll
    for (int nt = 0; nt < 6; nt++){
      const int sect = nt >> 1;                 // 0=q 1=k 2=v
      const int d = (nt & 1)*16 + l15;          // 0..31 within head
      const int wrow = sect*96 + h*32 + d;      // row of qkv_w (288x96)
      short8 w0, w1, w2;
      if constexpr (PRE){
        const bf16* wp = wQ + wrow*96 + quad*8;
        w0 = *(const short8*)(wp);
        w1 = *(const short8*)(wp + 32);
        w2 = *(const short8*)(wp + 64);
      } else {
        const float* wp = qkvw + wrow*96 + quad*8;
        w0 = ldw8(wp); w1 = ldw8(wp + 32); w2 = ldw8(wp + 64);
      }
      float bias = qkvb[wrow];
      if (PRE && sect == 0) bias *= QSC;        // match pre-scaled q-weights
      const f32x4 bacc = {bias, bias, bias, bias};
      #pragma unroll
      for (int wv = 0; wv < 2; wv++){
        f32x4 acc = bacc;
        acc = MFMA16(A0[wv], w0, acc);
        acc = MFMA16(A1[wv], w1, acc);
        acc = MFMA16(A2[wv], w2, acc);
        if (sect == 0){
          #pragma unroll
          for (int r = 0; r < 4; r++){
            const float qv = PRE ? acc[r] : acc[r]*QSC;
            *(bf16*)(s_q + (wv*64 + row0 + r)*80 + ((d*2) ^ cwz)) = f2b(qv);
          }
        } else if (sect == 1){
          #pragma unroll
          for (int r = 0; r < 4; r++)
            *(bf16*)(s_k + (wv*64 + row0 + r)*80 + ((d*2) ^ cwz)) = f2b(acc[r]);
        } else {
          short4v pk;
          #pragma unroll
          for (int r = 0; r < 4; r++) pk[r] = f2s(acc[r]);
          *(short4v*)(s_vt + wv*4608 + d*144 + ((row0*2) ^ KEYR(d))) = pk;   // V^T
        }
      }
    }
    __syncthreads();   // k, vt (cross-wave) ready

    // ---- scores + softmax (no-max, clamped) + PV, fused; bias shared across windows ----
    {
      f32x4 bvv[4];
      if constexpr (PRE){
        #pragma unroll
        for (int nt = 0; nt < 4; nt++)
          #pragma unroll
          for (int r = 0; r < 4; r++)
            bvv[nt][r] = btab[(h*64 + row0 + r)*64 + nt*16 + l15];
      } else {
        #pragma unroll
        for (int nt = 0; nt < 4; nt++){
          const int col = nt*16 + l15, ci = col >> 3, cj = col & 7;
          #pragma unroll
          for (int r = 0; r < 4; r++){
            const int row = row0 + r, ri = row >> 3, rj = row & 7;
            const int rel = (ri - ci + 7)*15 + (rj - cj + 7);
            bvv[nt][r] = rpb[rel*3 + h];
          }
        }
      }
      #pragma unroll
      for (int wv = 0; wv < 2; wv++){
        const int q16 = (quad*16) ^ rwz;
        const short8 aq = *(const short8*)(s_q + (wv*64 + m0 + l15)*80 + q16);
        f32x4 sc[4];
        #pragma unroll
        for (int nt = 0; nt < 4; nt++){
          const short8 bk = *(const short8*)(s_k + (wv*64 + nt*16 + l15)*80 + q16);
          sc[nt] = MFMA16(aq, bk, bvv[nt]);   // rel-pos bias folded into C-input
        }
        // softmax: exp(s)/sum — max-sub dropped (|s|~O(3) here); clamp for safety
        #pragma unroll
        for (int r = 0; r < 4; r++){
          const float e0 = __expf(fminf(sc[0][r], 80.f));
          const float e1 = __expf(fminf(sc[1][r], 80.f));
          const float e2 = __expf(fminf(sc[2][r], 80.f));
          const float e3 = __expf(fminf(sc[3][r], 80.f));
          float sm = e0+e1+e2+e3;
          sm += __shfl_xor(sm, 1);
          sm += __shfl_xor(sm, 2);
          sm += __shfl_xor(sm, 4);
          sm += __shfl_xor(sm, 8);
          const float rs = 1.f / sm;
          char* pb = s_p + (wv*64 + row0 + r)*144;
          *(bf16*)(pb + ((      l15*2) ^ cwz)) = f2b(e0*rs);
          *(bf16*)(pb + (( 32 + l15*2) ^ cwz)) = f2b(e1*rs);
          *(bf16*)(pb + (( 64 + l15*2) ^ cwz)) = f2b(e2*rs);
          *(bf16*)(pb + (( 96 + l15*2) ^ cwz)) = f2b(e3*rs);
        }

        // PV : p own-wave rows; vt barrier-protected
        const char* pr = s_p + (wv*64 + m0 + l15)*144;
        const short8 p0 = *(const short8*)(pr + q16);
        const short8 p1 = *(const short8*)(pr + q16 + 64);
        #pragma unroll
        for (int nt = 0; nt < 2; nt++){
          const char* vr = s_vt + wv*4608 + (nt*16 + l15)*144;
          f32x4 acc = zac;
          acc = MFMA16(p0, *(const short8*)(vr + q16), acc);
          acc = MFMA16(p1, *(const short8*)(vr + q16 + 64), acc);
          #pragma unroll
          for (int r = 0; r < 4; r++)
            *(bf16*)(s_ao + (wv*64 + row0 + r)*208 + (((h*32 + nt*16 + l15)*2) ^ cwz)) = f2b(acc[r]);
        }
      }
    }
    __syncthreads();   // protect q/k/vt overwrite (next head) / R0 overwrite (proj)
  }

  // ---------------- proj with FUSED LN2 epilogue: stats via l15-shuffles ----
  {
    short8 B0[2], B1[2], B2[2];
    #pragma unroll
    for (int wv = 0; wv < 2; wv++){
      const char* bp = s_ao + (wv*64 + m0 + l15)*208;
      const int q16 = (quad*16) ^ rwz;
      B0[wv] = *(const short8*)(bp + q16);
      B1[wv] = *(const short8*)(bp + q16 + 64);
      B2[wv] = *(const short8*)(bp + q16 + 128);
    }
    float g6[6], b6[6];
    #pragma unroll
    for (int nt = 0; nt < 6; nt++){
      g6[nt] = n2g[nt*16 + l15];
      b6[nt] = n2b[nt*16 + l15];
    }
    float vals[2][6][4];
    #pragma unroll
    for (int nt = 0; nt < 6; nt++){
      const int wrow = nt*16 + l15;
      short8 w0, w1, w2;
      if constexpr (PRE){
        const bf16* wp = wP + wrow*96 + quad*8;
        w0 = *(const short8*)(wp);
        w1 = *(const short8*)(wp + 32);
        w2 = *(const short8*)(wp + 64);
      } else {
        const float* wp = projw + wrow*96 + quad*8;
        w0 = ldw8(wp); w1 = ldw8(wp + 32); w2 = ldw8(wp + 64);
      }
      const float bias = projb[wrow];
      const f32x4 bacc = {bias, bias, bias, bias};
      #pragma unroll
      for (int wv = 0; wv < 2; wv++){
        f32x4 acc = bacc;
        acc = MFMA16(B0[wv], w0, acc);
        acc = MFMA16(B1[wv], w1, acc);
        acc = MFMA16(B2[wv], w2, acc);
        #pragma unroll
        for (int r = 0; r < 4; r++) vals[wv][nt][r] = acc[r];
      }
    }
    // row stats: each physical row lives in the 16 l15-lanes of one quad (6 vals each)
    #pragma unroll
    for (int wv = 0; wv < 2; wv++){
      #pragma unroll
      for (int r = 0; r < 4; r++){
        float sm = 0.f, sq = 0.f;
        #pragma unroll
        for (int nt = 0; nt < 6; nt++){ const float v = vals[wv][nt][r]; sm += v; sq += v*v; }
        sm += __shfl_xor(sm, 1); sm += __shfl_xor(sm, 2);
        sm += __shfl_xor(sm, 4); sm += __shfl_xor(sm, 8);
        sq += __shfl_xor(sq, 1); sq += __shfl_xor(sq, 2);
        sq += __shfl_xor(sq, 4); sq += __shfl_xor(sq, 8);
        const float mu  = sm * (1.f/96.f);
        const float inv = rsqrtf(fmaxf(sq*(1.f/96.f) - mu*mu, 0.f) + EPS);
        char* ob = s_a + (wv*64 + row0 + r)*208;
        #pragma unroll
        for (int nt = 0; nt < 6; nt++)
          *(bf16*)(ob + (((nt*16 + l15)*2) ^ cwz)) =
              f2b((vals[wv][nt][r] - mu) * inv * g6[nt] + b6[nt]);
      }
    }
  }
  __syncthreads();   // all s_ao/vt/p reads done before s_h overwrites R1/R2

  // ---------------- fc1 + GELU -> s_h[128] rows of 400 B (own-wave rows) ----
  {
    short8 C0[2], C1[2], C2[2];
    #pragma unroll
    for (int wv = 0; wv < 2; wv++){
      const char* cp = s_a + (wv*64 + m0 + l15)*208;
      const int q16 = (quad*16) ^ rwz;
      C0[wv] = *(const short8*)(cp + q16);
      C1[wv] = *(const short8*)(cp + q16 + 64);
      C2[wv] = *(const short8*)(cp + q16 + 128);
    }
    #pragma unroll
    for (int nt = 0; nt < 12; nt++){
      const int wrow = nt*16 + l15;
      short8 w0, w1, w2;
      if constexpr (PRE){
        const bf16* wp = wF1 + wrow*96 + quad*8;
        w0 = *(const short8*)(wp);
        w1 = *(const short8*)(wp + 32);
        w2 = *(const short8*)(wp + 64);
      } else {
        const float* wp = fc1w + wrow*96 + quad*8;
        w0 = ldw8(wp); w1 = ldw8(wp + 32); w2 = ldw8(wp + 64);
      }
      const float bias = fc1b[wrow];
      const f32x4 bacc = {bias, bias, bias, bias};
      #pragma unroll
      for (int wv = 0; wv < 2; wv++){
        f32x4 acc = bacc;
        acc = MFMA16(C0[wv], w0, acc);
        acc = MFMA16(C1[wv], w1, acc);
        acc = MFMA16(C2[wv], w2, acc);
        #pragma unroll
        for (int r = 0; r < 4; r++){
          const float v = acc[r];
          // GELU via tanh identity: g = v - v/(e^{2y}+1), y = 0.7978845608*(v+0.044715 v^3)
          const float t = __expf(1.5957691216057308f * (v + 0.044715f*v*v*v));
          const float g = v - v * (1.f / (t + 1.f));
          *(bf16*)(s_h + (wv*64 + row0 + r)*400 + ((wrow*2) ^ cwz)) = f2b(g);
        }
      }
    }
  }
  __syncthreads();   // all waves' s_a reads done before s_at overwrites R0

  // ---------------- fc2: K=192 -> s_at transposed [96] rows of 272 B (plain) ----
  {
    short8 F[2][6];
    #pragma unroll
    for (int wv = 0; wv < 2; wv++){
      const char* fp = s_h + (wv*64 + m0 + l15)*400;
      const int q16 = (quad*16) ^ rwz;
      #pragma unroll
      for (int ks = 0; ks < 6; ks++)
        F[wv][ks] = *(const short8*)(fp + ks*64 + q16);
    }
    #pragma unroll
    for (int nt = 0; nt < 6; nt++){
      const int wrow = nt*16 + l15;
      short8 w[6];
      if constexpr (PRE){
        const bf16* wp = wF2 + wrow*192 + quad*8;
        #pragma unroll
        for (int ks = 0; ks < 6; ks++) w[ks] = *(const short8*)(wp + ks*32);
      } else {
        const float* wp = fc2w + wrow*192 + quad*8;
        #pragma unroll
        for (int ks = 0; ks < 6; ks++) w[ks] = ldw8(wp + ks*32);
      }
      const float bias = fc2b[wrow];
      const f32x4 bacc = {bias, bias, bias, bias};
      #pragma unroll
      for (int wv = 0; wv < 2; wv++){
        f32x4 acc = bacc;
        #pragma unroll
        for (int ks = 0; ks < 6; ks++)
          acc = MFMA16(F[wv][ks], w[ks], acc);
        short4v pk;
        #pragma unroll
        for (int r = 0; r < 4; r++) pk[r] = f2s(acc[r]);
        *(short4v*)(s_at + wrow*272 + (wv*64 + row0)*2) = pk;   // [c][token]
      }
    }
  }
  __syncthreads();

  // ---------------- writeout: fp32 residual add from registers, window merge ----
  #pragma unroll
  for (int it = 0; it < 12; it++){
    const int idx4 = it*256 + tid;
    const int c = idx4 >> 5, r = idx4 & 31;
    const int irow = r >> 2, j0 = (r & 3) * 4;
    const int t0 = (j0 >> 3)*64 + irow*8 + (j0 & 7);
    const short4v pv = *(const short4v*)(s_at + c*272 + t0*2);
    const size_t g = base + (size_t)c*65536 + irow*256 + j0;
    const float4 xv = xsave[it];
    float4 ov;
    ov.x = xv.x + s2f(pv[0]);
    ov.y = xv.y + s2f(pv[1]);
    ov.z = xv.z + s2f(pv[2]);
    ov.w = xv.w + s2f(pv[3]);
    *(float4*)(out + g) = ov;
  }
}

extern "C" void kernel_launch(void* const* d_in, const int* in_sizes, int n_in,
                              void* d_out, int out_size, void* d_ws, size_t ws_size,
                              hipStream_t stream) {
  const float* x     = (const float*)d_in[0];
  const float* qkvw  = (const float*)d_in[1];
  const float* qkvb  = (const float*)d_in[2];
  const float* projw = (const float*)d_in[3];
  const float* projb = (const float*)d_in[4];
  const float* rpb   = (const float*)d_in[5];
  const float* n1g   = (const float*)d_in[6];
  const float* n1b   = (const float*)d_in[7];
  const float* n2g   = (const float*)d_in[8];
  const float* n2b   = (const float*)d_in[9];
  const float* fc1w  = (const float*)d_in[10];
  const float* fc1b  = (const float*)d_in[11];
  const float* fc2w  = (const float*)d_in[12];
  const float* fc2b  = (const float*)d_in[13];
  float* out = (float*)d_out;

  if (ws_size >= WS_NEEDED && d_ws != nullptr) {
    bf16*  wbf  = (bf16*)d_ws;
    float* btab = (float*)((char*)d_ws + BTAB_BYTE_OFF);
    init_ws_kernel<<<dim3(288), dim3(256), 0, stream>>>(
        qkvw, projw, fc1w, fc2w, rpb, wbf, btab);
    swin_block_kernel<true><<<dim3(4096), dim3(TPB), 0, stream>>>(
        x, qkvw, qkvb, projw, projb, rpb,
        n1g, n1b, n2g, n2b, fc1w, fc1b, fc2w, fc2b, out, wbf, btab);
  } else {
    swin_block_kernel<false><<<dim3(4096), dim3(TPB), 0, stream>>>(
        x, qkvw, qkvb, projw, projb, rpb,
        n1g, n1b, n2g, n2b, fc1w, fc1b, fc2w, fc2b, out,
        (const bf16*)nullptr, (const float*)nullptr);
  }
}